// Round 5
// baseline (388.077 us; speedup 1.0000x reference)
//
#include <hip/hip_runtime.h>

#define D 64
#define WQ_BITS 15
#define WQ_MAX 32767.0f
#define NSHARDS 8
#define CAP32 32        // bucket capacity (deg~Poisson(16); P(>32)~1e-4 ->
                        // ~10 nodes / ~30 edges to overflow fixup)

typedef int    int4v    __attribute__((ext_vector_type(4)));
typedef float  float4v  __attribute__((ext_vector_type(4)));
typedef ushort ushort8v __attribute__((ext_vector_type(8)));

__device__ __forceinline__ ushort f2bf(float x) {
    unsigned u = __float_as_uint(x);
    unsigned r = (u + 0x7fff + ((u >> 16) & 1)) >> 16;  // round-to-nearest-even
    return (ushort)r;
}
__device__ __forceinline__ float bf2f(ushort u) {
    return __uint_as_float(((unsigned)u) << 16);
}

// ---------------------------------------------------------------------------
// Scatter (round-1 verified config, 78us): node-sharded, shard=blockIdx%8 ->
// one XCD owns each node's bucket row (plain stores legal: single-L2 dirty).
// Coherence ledger: r2 plain-store cross-XCD = replay corruption; r3 agent-
// scope store = 64B write-through/store (96us); r4 XCD-partition = L2 capacity
// churn (127us, WRITE=64B/edge). The 8x edge scan is the price of coherent
// plain stores; streams are L3-resident (FETCH 9.4MB single-pass) so the scan
// cost is instruction/latency, not HBM.
__global__ __launch_bounds__(256) void shard_scatter_kernel(
    const int* __restrict__ src, const int* __restrict__ dst,
    const float* __restrict__ w, int* __restrict__ cursor,
    unsigned* __restrict__ ovBits, unsigned* __restrict__ pairs,
    int E, int N)
{
    int shard   = blockIdx.x & (NSHARDS - 1);
    int slice   = blockIdx.x >> 3;
    int nSlices = gridDim.x >> 3;
    int n8 = (N + NSHARDS - 1) / NSHARDS;
    int lo = shard * n8;
    int hi = min(N, lo + n8);

    int e4 = E >> 2;
    for (int gi = slice * 256 + threadIdx.x; gi < e4; gi += nSlices * 256) {
        int e0 = gi * 4;
        int4v   d4 = __builtin_nontemporal_load((const int4v*)&dst[e0]);
        int4v   s4 = __builtin_nontemporal_load((const int4v*)&src[e0]);
        float4v w4 = __builtin_nontemporal_load((const float4v*)&w[e0]);
        #pragma unroll
        for (int i = 0; i < 4; ++i) {
            int d = d4[i];
            if (d >= lo && d < hi) {
                int e = e0 + i;
                int pos = atomicAdd(&cursor[d], 1);
                if (pos < CAP32) {
                    float wv = fminf(fmaxf(w4[i], 0.f), 1.f);
                    unsigned wq = (unsigned)(wv * WQ_MAX + 0.5f);
                    pairs[(size_t)d * CAP32 + pos] =
                        ((unsigned)s4[i] << WQ_BITS) | wq;
                } else {
                    atomicOr(&ovBits[e >> 5], 1u << (e & 31));
                }
            }
        }
    }
    for (int e = e4 * 4 + slice * 256 + threadIdx.x; e < E; e += nSlices * 256) {
        int d = dst[e];
        if (d >= lo && d < hi) {
            int pos = atomicAdd(&cursor[d], 1);
            if (pos < CAP32) {
                float wv = fminf(fmaxf(w[e], 0.f), 1.f);
                unsigned wq = (unsigned)(wv * WQ_MAX + 0.5f);
                pairs[(size_t)d * CAP32 + pos] =
                    ((unsigned)src[e] << WQ_BITS) | wq;
            } else {
                atomicOr(&ovBits[e >> 5], 1u << (e & 31));
            }
        }
    }
}

// ---------------------------------------------------------------------------
// bf16 copy of h (gather payload for the fused GEMM). 8 elems/thread.
__global__ __launch_bounds__(256) void hbf_kernel(
    const float* __restrict__ h, ushort* __restrict__ hbf, int total8)
{
    for (int i = blockIdx.x * 256 + threadIdx.x; i < total8;
         i += gridDim.x * 256) {
        float4 a = *(const float4*)&h[(size_t)i * 8];
        float4 c = *(const float4*)&h[(size_t)i * 8 + 4];
        ushort8v v;
        v[0] = f2bf(a.x); v[1] = f2bf(a.y); v[2] = f2bf(a.z); v[3] = f2bf(a.w);
        v[4] = f2bf(c.x); v[5] = f2bf(c.y); v[6] = f2bf(c.z); v[7] = f2bf(c.w);
        *(ushort8v*)&hbf[(size_t)i * 8] = v;
    }
}

// ---------------------------------------------------------------------------
// Round-14 fused GEMM+gather. Replaces {gemm_fused + final_agg32 + g array}:
// out[n] = b + h[n]@W1^T + agg[n]@W2^T,  agg[n] = sum_bucket wq*hbf[src].
// Eliminates the 51MB out-RMW and 25.6MB g traffic of the 2-kernel pipeline.
// Per block: 64 nodes, 4 waves; wave v gather-aggregates nodes v*16..v*16+15
// (MLP-16 batched gathers, one wave per node) into At, then 2x K=64 LDS
// matmul. LDS = 32K Wt + 16K Xt + 17K At = 65KB -> 2 blocks/CU.
__global__ __launch_bounds__(256) void gemm_gather_kernel(
    const float* __restrict__ h, const float* __restrict__ W,
    const float* __restrict__ b, const ushort* __restrict__ hbf,
    const unsigned* __restrict__ pairs, const int* __restrict__ cursor,
    float* __restrict__ out, int N)
{
    __shared__ float Wt[128 * 64];   // Wt[k*64+j] = W[j*128+k]
    __shared__ float Xt[64 * 64];    // Xt[k*64+n] = h[n0+n][k]
    __shared__ float At[64 * 68];    // At[k*68+n] = agg[n0+n][k]; pad 68:
                                     // write banks (4*lane+ln)%32 -> 8-way
                                     // (vs 64-way at stride 64), reads stay
                                     // 16B-aligned for float4.
    int tid  = threadIdx.x;
    int lane = tid & 63;
    int wv   = tid >> 6;
    int n0blk = blockIdx.x * 64;

    for (int idx = tid; idx < 128 * 64; idx += 256) {
        int j = idx & 63;
        int k = idx >> 6;
        Wt[k * 64 + j] = W[j * 128 + k];
    }
    {
        int n = tid & 63;
        int krow = tid >> 6;
        int nn = min(n0blk + n, N - 1);
        #pragma unroll
        for (int c = 0; c < 4; ++c) {
            int k0 = (krow + c * 4) * 4;
            float4 v = *(const float4*)&h[(size_t)nn * D + k0];
            Xt[(k0 + 0) * 64 + n] = v.x;
            Xt[(k0 + 1) * 64 + n] = v.y;
            Xt[(k0 + 2) * 64 + n] = v.z;
            Xt[(k0 + 3) * 64 + n] = v.w;
        }
    }

    // ---- gather-aggregate phase (overlaps the staging loads above) ----
    const float wscale = 1.0f / WQ_MAX;
    for (int ln = wv * 16; ln < wv * 16 + 16; ++ln) {
        int n = n0blk + ln;
        int cnt = 0;
        unsigned mycode = 0;
        if (n < N) {
            cnt = min(cursor[n], CAP32);
            if (lane < CAP32) mycode = pairs[(size_t)n * CAP32 + lane];
        }
        float acc = 0.f;
        int j = 0;
        for (; j + 16 <= cnt; j += 16) {
            unsigned c[16];
            float v[16];
            #pragma unroll
            for (int u = 0; u < 16; ++u) c[u] = __shfl(mycode, j + u);
            #pragma unroll
            for (int u = 0; u < 16; ++u)
                v[u] = bf2f(hbf[(size_t)(c[u] >> WQ_BITS) * D + lane]);
            #pragma unroll
            for (int u = 0; u < 16; ++u)
                acc += (float)(c[u] & 0x7fffu) * wscale * v[u];
        }
        for (; j + 4 <= cnt; j += 4) {
            unsigned c[4];
            float v[4];
            #pragma unroll
            for (int u = 0; u < 4; ++u) c[u] = __shfl(mycode, j + u);
            #pragma unroll
            for (int u = 0; u < 4; ++u)
                v[u] = bf2f(hbf[(size_t)(c[u] >> WQ_BITS) * D + lane]);
            #pragma unroll
            for (int u = 0; u < 4; ++u)
                acc += (float)(c[u] & 0x7fffu) * wscale * v[u];
        }
        for (; j < cnt; ++j) {
            unsigned c = __shfl(mycode, j);
            acc += (float)(c & 0x7fffu) * wscale *
                   bf2f(hbf[(size_t)(c >> WQ_BITS) * D + lane]);
        }
        At[lane * 68 + ln] = acc;   // lane = k index
    }
    __syncthreads();

    // ---- matmul phase: acc = b + Xt@W1 + At@W2 ----
    int j0 = (tid & 15) * 4;
    int nb = (tid >> 4) * 4;

    float4 bv = *(const float4*)&b[j0];
    float acc[4][4];
    #pragma unroll
    for (int i = 0; i < 4; ++i) {
        acc[i][0] = bv.x; acc[i][1] = bv.y; acc[i][2] = bv.z; acc[i][3] = bv.w;
    }

    #pragma unroll 4
    for (int k = 0; k < 64; ++k) {
        float4 xv = *(const float4*)&Xt[k * 64 + nb];
        float4 av = *(const float4*)&At[k * 68 + nb];
        float4 w1 = *(const float4*)&Wt[k * 64 + j0];
        float4 w2 = *(const float4*)&Wt[(k + 64) * 64 + j0];
        #pragma unroll
        for (int i = 0; i < 4; ++i) {
            float x = (&xv.x)[i];
            float a = (&av.x)[i];
            acc[i][0] += x * w1.x + a * w2.x;
            acc[i][1] += x * w1.y + a * w2.y;
            acc[i][2] += x * w1.z + a * w2.z;
            acc[i][3] += x * w1.w + a * w2.w;
        }
    }

    #pragma unroll
    for (int i = 0; i < 4; ++i) {
        int n = n0blk + nb + i;
        if (n < N) {
            *(float4*)&out[(size_t)n * D + j0] =
                make_float4(acc[i][0], acc[i][1], acc[i][2], acc[i][3]);
        }
    }
}

// ---------------------------------------------------------------------------
// Overflow fixup (post-GEMM): out[d] += w * (hbf[s] @ W2^T) for each edge that
// missed its bucket (~30 edges at CAP32). Wave-cooperative: lane j owns out
// column j; m_k broadcast via shfl; W2[j][k] = W[j*128+64+k] (L2-hot, 32KB).
__global__ __launch_bounds__(256) void overflow_fix_kernel(
    const unsigned* __restrict__ ovBits, const int* __restrict__ src,
    const int* __restrict__ dst, const float* __restrict__ w,
    const ushort* __restrict__ hbf, const float* __restrict__ W,
    float* __restrict__ out, int numWords)
{
    int lane   = threadIdx.x & 63;
    int gwave  = (blockIdx.x * 256 + threadIdx.x) >> 6;
    int nwaves = (gridDim.x * 256) >> 6;
    for (int wi = gwave; wi < numWords; wi += nwaves) {
        unsigned bits = ovBits[wi];   // wave-uniform
        while (bits) {
            int bit = __ffs(bits) - 1;
            bits &= bits - 1;
            int e = wi * 32 + bit;
            int s = src[e], d = dst[e];
            float wvv = w[e];
            float hs = bf2f(hbf[(size_t)s * D + lane]);
            float acc = 0.f;
            #pragma unroll 8
            for (int k = 0; k < 64; ++k) {
                float hk = __shfl(hs, k, 64);
                acc += hk * W[lane * 128 + 64 + k];
            }
            atomicAdd(&out[(size_t)d * D + lane], wvv * acc);
        }
    }
}

// ---------------------------------------------------------------------------
// Fallback path (small ws / big N): round-1 kernels, known-good.
__global__ __launch_bounds__(256) void edge_scatter_kernel(
    const float* __restrict__ h, const float* __restrict__ w,
    const int* __restrict__ src, const int* __restrict__ dst,
    float* __restrict__ agg, int E)
{
    int e = blockIdx.x * 4 + (threadIdx.x >> 6);
    int lane = threadIdx.x & 63;
    if (e >= E) return;
    float val = w[e] * h[(size_t)src[e] * D + lane];
    atomicAdd(&agg[(size_t)dst[e] * D + lane], val);
}

__global__ __launch_bounds__(256) void out_linear_kernel(
    const float* __restrict__ h, const float* __restrict__ agg,
    const float* __restrict__ W, const float* __restrict__ b,
    float* __restrict__ out, int N)
{
    __shared__ float Wt[128 * 64];
    int lane = threadIdx.x & 63;
    int waveInBlock = threadIdx.x >> 6;
    int wavesPerBlock = blockDim.x >> 6;
    for (int idx = threadIdx.x; idx < 128 * 64; idx += blockDim.x) {
        int j = idx & 63;
        int k = idx >> 6;
        Wt[k * 64 + j] = W[j * 128 + k];
    }
    __syncthreads();
    float bj = b[lane];
    int wavesPerGrid = gridDim.x * wavesPerBlock;
    for (int n = blockIdx.x * wavesPerBlock + waveInBlock; n < N; n += wavesPerGrid) {
        float hreg = h[(size_t)n * D + lane];
        float areg = agg[(size_t)n * D + lane];
        float acc = bj;
        #pragma unroll
        for (int k = 0; k < 64; ++k) {
            float hk = __shfl(hreg, k, 64);
            float ak = __shfl(areg, k, 64);
            acc += hk * Wt[k * 64 + lane];
            acc += ak * Wt[(k + 64) * 64 + lane];
        }
        out[(size_t)n * D + lane] = acc;
    }
}

// ---------------------------------------------------------------------------
extern "C" void kernel_launch(void* const* d_in, const int* in_sizes, int n_in,
                              void* d_out, int out_size, void* d_ws, size_t ws_size,
                              hipStream_t stream) {
    const float* h   = (const float*)d_in[0];
    const float* w   = (const float*)d_in[1];
    const int*   src = (const int*)d_in[2];
    const int*   dst = (const int*)d_in[3];
    const float* W   = (const float*)d_in[4];
    const float* b   = (const float*)d_in[5];
    float* out = (float*)d_out;

    int N = in_sizes[0] / D;
    int E = in_sizes[1];
    int numWords = (E + 31) / 32;

    auto align256 = [](size_t x) { return (x + 255) & ~(size_t)255; };
    size_t cursorB = align256((size_t)N * 4);
    size_t ovB     = align256((size_t)numWords * 4);
    size_t pairsB  = align256((size_t)N * CAP32 * 4);
    size_t hbfB    = align256((size_t)N * D * 2);
    size_t need = cursorB + ovB + pairsB + hbfB;

    if (ws_size >= need && N <= (1 << 17)) {
        char* p = (char*)d_ws;
        int*      cursor = (int*)p;       p += cursorB;
        unsigned* ovBits = (unsigned*)p;  p += ovB;
        unsigned* pairs  = (unsigned*)p;  p += pairsB;
        ushort*   hbf    = (ushort*)p;

        hipMemsetAsync(cursor, 0, cursorB + ovB, stream);

        hbf_kernel<<<2048, 256, 0, stream>>>(h, hbf, N * D / 8);
        shard_scatter_kernel<<<4096, 256, 0, stream>>>(src, dst, w, cursor,
                                                       ovBits, pairs, E, N);
        gemm_gather_kernel<<<(N + 63) / 64, 256, 0, stream>>>(
            h, W, b, hbf, pairs, cursor, out, N);
        overflow_fix_kernel<<<64, 256, 0, stream>>>(ovBits, src, dst, w, hbf,
                                                    W, out, numWords);
    } else {
        float* agg = out;
        hipMemsetAsync(agg, 0, (size_t)N * D * 4, stream);
        edge_scatter_kernel<<<(E + 3) / 4, 256, 0, stream>>>(h, w, src, dst, agg, E);
        out_linear_kernel<<<2048, 256, 0, stream>>>(h, agg, W, b, out, N);
    }
}

// Round 6
// 370.741 us; speedup vs baseline: 1.0468x; 1.0468x over previous
//
#include <hip/hip_runtime.h>

#define D 64
#define WQ_BITS 15
#define WQ_MAX 32767.0f
#define NSHARDS 8
#define CAP32 32        // bucket capacity (deg~Poisson(16); P(>32)~1e-4 ->
                        // ~10 nodes / ~30 edges to overflow fixup)

typedef int    int4v    __attribute__((ext_vector_type(4)));
typedef float  float4v  __attribute__((ext_vector_type(4)));
typedef ushort ushort8v __attribute__((ext_vector_type(8)));

__device__ __forceinline__ ushort f2bf(float x) {
    unsigned u = __float_as_uint(x);
    unsigned r = (u + 0x7fff + ((u >> 16) & 1)) >> 16;  // round-to-nearest-even
    return (ushort)r;
}
__device__ __forceinline__ float bf2f(ushort u) {
    return __uint_as_float(((unsigned)u) << 16);
}
// wave-uniform lane read (k is uniform: loop counter) -> v_readlane to SGPR,
// cheaper than ds_bpermute (__shfl) on the DS pipe.
__device__ __forceinline__ float rlane(float v, int k) {
    return __uint_as_float(__builtin_amdgcn_readlane(__float_as_uint(v), k));
}

// ---------------------------------------------------------------------------
// Scatter (round-1 verified config, 78us): node-sharded, shard=blockIdx%8 ->
// one XCD owns each node's bucket row (plain stores legal: single-L2 dirty).
// Coherence ledger: r2 plain-store cross-XCD = replay corruption; r3 agent-
// scope store = 64B write-through/store (96us); r4 XCD-partition = L2 capacity
// churn (127us, WRITE=64B/edge). The 8x edge scan is the price of coherent
// plain stores; streams are L3-resident so the scan is instr/latency cost.
__global__ __launch_bounds__(256) void shard_scatter_kernel(
    const int* __restrict__ src, const int* __restrict__ dst,
    const float* __restrict__ w, int* __restrict__ cursor,
    unsigned* __restrict__ ovBits, unsigned* __restrict__ pairs,
    int E, int N)
{
    int shard   = blockIdx.x & (NSHARDS - 1);
    int slice   = blockIdx.x >> 3;
    int nSlices = gridDim.x >> 3;
    int n8 = (N + NSHARDS - 1) / NSHARDS;
    int lo = shard * n8;
    int hi = min(N, lo + n8);

    int e4 = E >> 2;
    for (int gi = slice * 256 + threadIdx.x; gi < e4; gi += nSlices * 256) {
        int e0 = gi * 4;
        int4v   d4 = __builtin_nontemporal_load((const int4v*)&dst[e0]);
        int4v   s4 = __builtin_nontemporal_load((const int4v*)&src[e0]);
        float4v w4 = __builtin_nontemporal_load((const float4v*)&w[e0]);
        #pragma unroll
        for (int i = 0; i < 4; ++i) {
            int d = d4[i];
            if (d >= lo && d < hi) {
                int e = e0 + i;
                int pos = atomicAdd(&cursor[d], 1);
                if (pos < CAP32) {
                    float wv = fminf(fmaxf(w4[i], 0.f), 1.f);
                    unsigned wq = (unsigned)(wv * WQ_MAX + 0.5f);
                    pairs[(size_t)d * CAP32 + pos] =
                        ((unsigned)s4[i] << WQ_BITS) | wq;
                } else {
                    atomicOr(&ovBits[e >> 5], 1u << (e & 31));
                }
            }
        }
    }
    for (int e = e4 * 4 + slice * 256 + threadIdx.x; e < E; e += nSlices * 256) {
        int d = dst[e];
        if (d >= lo && d < hi) {
            int pos = atomicAdd(&cursor[d], 1);
            if (pos < CAP32) {
                float wv = fminf(fmaxf(w[e], 0.f), 1.f);
                unsigned wq = (unsigned)(wv * WQ_MAX + 0.5f);
                pairs[(size_t)d * CAP32 + pos] =
                    ((unsigned)src[e] << WQ_BITS) | wq;
            } else {
                atomicOr(&ovBits[e >> 5], 1u << (e & 31));
            }
        }
    }
}

// ---------------------------------------------------------------------------
// bf16 copy of h (gather payload). 8 elems/thread.
__global__ __launch_bounds__(256) void hbf_kernel(
    const float* __restrict__ h, ushort* __restrict__ hbf, int total8)
{
    for (int i = blockIdx.x * 256 + threadIdx.x; i < total8;
         i += gridDim.x * 256) {
        float4 a = *(const float4*)&h[(size_t)i * 8];
        float4 c = *(const float4*)&h[(size_t)i * 8 + 4];
        ushort8v v;
        v[0] = f2bf(a.x); v[1] = f2bf(a.y); v[2] = f2bf(a.z); v[3] = f2bf(a.w);
        v[4] = f2bf(c.x); v[5] = f2bf(c.y); v[6] = f2bf(c.z); v[7] = f2bf(c.w);
        *(ushort8v*)&hbf[(size_t)i * 8] = v;
    }
}

// ---------------------------------------------------------------------------
// Round-15 fused node kernel: one WAVE per node (r5 post-mortem: the block-
// GEMM fusion at 65KB LDS = 8 waves/CU strangled the latency-bound gather;
// occupancy 18%, 600K At bank conflicts). Here:
//   out[n] = b + sum_k h[n][k]*W1[k][:] + sum_k agg[n][k]*W2[k][:]
//   agg[n] = sum_bucket wq * bf16(h[src])   (register, per-lane feature)
// Matvec reads Wt2[k][j]={W1,W2} float2 pairs: 1 ds_read_b64/k (conflict-
// free), x_k/a_k via v_readlane (uniform k, SALU-cheap, no DS op).
// LDS 32KB -> 5 blocks/CU = 20 waves/CU; out written exactly once.
__global__ __launch_bounds__(256) void fused_node_kernel(
    const float* __restrict__ h, const float* __restrict__ W,
    const float* __restrict__ b, const ushort* __restrict__ hbf,
    const unsigned* __restrict__ pairs, const int* __restrict__ cursor,
    float* __restrict__ out, int N)
{
    __shared__ float Wt2[64 * 128];  // Wt2[k*128 + j*2 + {0,1}] = {W1[j][k], W2[j][k]}
    int tid  = threadIdx.x;
    int lane = tid & 63;
    int wv   = tid >> 6;

    // stage: lanes take j=0..63 for fixed k -> LDS float2 writes consecutive
    // (conflict-free); W reads are 512B-strided but W is 32KB L2-resident.
    for (int idx = tid; idx < 64 * 64; idx += 256) {
        int j = idx & 63;
        int k = idx >> 6;
        *(float2*)&Wt2[k * 128 + j * 2] =
            make_float2(W[j * 128 + k], W[j * 128 + 64 + k]);
    }
    __syncthreads();

    float bj = b[lane];
    const float wscale = 1.0f / WQ_MAX;
    int nwaves = gridDim.x * 4;

    for (int n = blockIdx.x * 4 + wv; n < N; n += nwaves) {
        int cnt = min(cursor[n], CAP32);
        unsigned mycode = (lane < CAP32) ? pairs[(size_t)n * CAP32 + lane] : 0u;
        float hreg = h[(size_t)n * D + lane];

        // gather-aggregate into register (lane = feature index)
        float areg = 0.f;
        int j = 0;
        for (; j + 16 <= cnt; j += 16) {
            unsigned c[16];
            float v[16];
            #pragma unroll
            for (int u = 0; u < 16; ++u) c[u] = __shfl(mycode, j + u);
            #pragma unroll
            for (int u = 0; u < 16; ++u)
                v[u] = bf2f(hbf[(size_t)(c[u] >> WQ_BITS) * D + lane]);
            #pragma unroll
            for (int u = 0; u < 16; ++u)
                areg += (float)(c[u] & 0x7fffu) * wscale * v[u];
        }
        for (; j + 4 <= cnt; j += 4) {
            unsigned c[4];
            float v[4];
            #pragma unroll
            for (int u = 0; u < 4; ++u) c[u] = __shfl(mycode, j + u);
            #pragma unroll
            for (int u = 0; u < 4; ++u)
                v[u] = bf2f(hbf[(size_t)(c[u] >> WQ_BITS) * D + lane]);
            #pragma unroll
            for (int u = 0; u < 4; ++u)
                areg += (float)(c[u] & 0x7fffu) * wscale * v[u];
        }
        for (; j < cnt; ++j) {
            unsigned c = __shfl(mycode, j);
            areg += (float)(c & 0x7fffu) * wscale *
                    bf2f(hbf[(size_t)(c >> WQ_BITS) * D + lane]);
        }

        // matvec: acc_j = bj + sum_k x_k*W1[k][j] + a_k*W2[k][j]
        float acc = bj;
        #pragma unroll 8
        for (int k = 0; k < 64; ++k) {
            float xk = rlane(hreg, k);
            float ak = rlane(areg, k);
            float2 wv2 = *(const float2*)&Wt2[k * 128 + lane * 2];
            acc += xk * wv2.x + ak * wv2.y;
        }
        out[(size_t)n * D + lane] = acc;
    }
}

// ---------------------------------------------------------------------------
// Overflow fixup (post-fused): out[d] += w * (bf16(h[s]) @ W2^T) per missed
// edge (~30 at CAP32). Wave-cooperative matvec, W2 L2-hot.
__global__ __launch_bounds__(256) void overflow_fix_kernel(
    const unsigned* __restrict__ ovBits, const int* __restrict__ src,
    const int* __restrict__ dst, const float* __restrict__ w,
    const ushort* __restrict__ hbf, const float* __restrict__ W,
    float* __restrict__ out, int numWords)
{
    int lane   = threadIdx.x & 63;
    int gwave  = (blockIdx.x * 256 + threadIdx.x) >> 6;
    int nwaves = (gridDim.x * 256) >> 6;
    for (int wi = gwave; wi < numWords; wi += nwaves) {
        unsigned bits = ovBits[wi];   // wave-uniform
        while (bits) {
            int bit = __ffs(bits) - 1;
            bits &= bits - 1;
            int e = wi * 32 + bit;
            int s = src[e], d = dst[e];
            float wvv = w[e];
            float hs = bf2f(hbf[(size_t)s * D + lane]);
            float acc = 0.f;
            #pragma unroll 8
            for (int k = 0; k < 64; ++k) {
                float hk = __shfl(hs, k, 64);
                acc += hk * W[lane * 128 + 64 + k];
            }
            atomicAdd(&out[(size_t)d * D + lane], wvv * acc);
        }
    }
}

// ---------------------------------------------------------------------------
// Fallback path (small ws / big N): round-1 kernels, known-good.
__global__ __launch_bounds__(256) void edge_scatter_kernel(
    const float* __restrict__ h, const float* __restrict__ w,
    const int* __restrict__ src, const int* __restrict__ dst,
    float* __restrict__ agg, int E)
{
    int e = blockIdx.x * 4 + (threadIdx.x >> 6);
    int lane = threadIdx.x & 63;
    if (e >= E) return;
    float val = w[e] * h[(size_t)src[e] * D + lane];
    atomicAdd(&agg[(size_t)dst[e] * D + lane], val);
}

__global__ __launch_bounds__(256) void out_linear_kernel(
    const float* __restrict__ h, const float* __restrict__ agg,
    const float* __restrict__ W, const float* __restrict__ b,
    float* __restrict__ out, int N)
{
    __shared__ float Wt[128 * 64];
    int lane = threadIdx.x & 63;
    int waveInBlock = threadIdx.x >> 6;
    int wavesPerBlock = blockDim.x >> 6;
    for (int idx = threadIdx.x; idx < 128 * 64; idx += blockDim.x) {
        int j = idx & 63;
        int k = idx >> 6;
        Wt[k * 64 + j] = W[j * 128 + k];
    }
    __syncthreads();
    float bj = b[lane];
    int wavesPerGrid = gridDim.x * wavesPerBlock;
    for (int n = blockIdx.x * wavesPerBlock + waveInBlock; n < N; n += wavesPerGrid) {
        float hreg = h[(size_t)n * D + lane];
        float areg = agg[(size_t)n * D + lane];
        float acc = bj;
        #pragma unroll
        for (int k = 0; k < 64; ++k) {
            float hk = __shfl(hreg, k, 64);
            float ak = __shfl(areg, k, 64);
            acc += hk * Wt[k * 64 + lane];
            acc += ak * Wt[(k + 64) * 64 + lane];
        }
        out[(size_t)n * D + lane] = acc;
    }
}

// ---------------------------------------------------------------------------
extern "C" void kernel_launch(void* const* d_in, const int* in_sizes, int n_in,
                              void* d_out, int out_size, void* d_ws, size_t ws_size,
                              hipStream_t stream) {
    const float* h   = (const float*)d_in[0];
    const float* w   = (const float*)d_in[1];
    const int*   src = (const int*)d_in[2];
    const int*   dst = (const int*)d_in[3];
    const float* W   = (const float*)d_in[4];
    const float* b   = (const float*)d_in[5];
    float* out = (float*)d_out;

    int N = in_sizes[0] / D;
    int E = in_sizes[1];
    int numWords = (E + 31) / 32;

    auto align256 = [](size_t x) { return (x + 255) & ~(size_t)255; };
    size_t cursorB = align256((size_t)N * 4);
    size_t ovB     = align256((size_t)numWords * 4);
    size_t pairsB  = align256((size_t)N * CAP32 * 4);
    size_t hbfB    = align256((size_t)N * D * 2);
    size_t need = cursorB + ovB + pairsB + hbfB;

    if (ws_size >= need && N <= (1 << 17)) {
        char* p = (char*)d_ws;
        int*      cursor = (int*)p;       p += cursorB;
        unsigned* ovBits = (unsigned*)p;  p += ovB;
        unsigned* pairs  = (unsigned*)p;  p += pairsB;
        ushort*   hbf    = (ushort*)p;

        hipMemsetAsync(cursor, 0, cursorB + ovB, stream);

        hbf_kernel<<<2048, 256, 0, stream>>>(h, hbf, N * D / 8);
        shard_scatter_kernel<<<4096, 256, 0, stream>>>(src, dst, w, cursor,
                                                       ovBits, pairs, E, N);
        fused_node_kernel<<<2048, 256, 0, stream>>>(h, W, b, hbf, pairs,
                                                    cursor, out, N);
        overflow_fix_kernel<<<64, 256, 0, stream>>>(ovBits, src, dst, w, hbf,
                                                    W, out, numWords);
    } else {
        float* agg = out;
        hipMemsetAsync(agg, 0, (size_t)N * D * 4, stream);
        edge_scatter_kernel<<<(E + 3) / 4, 256, 0, stream>>>(h, w, src, dst, agg, E);
        out_linear_kernel<<<2048, 256, 0, stream>>>(h, agg, W, b, out, N);
    }
}

// Round 7
// 261.471 us; speedup vs baseline: 1.4842x; 1.4179x over previous
//
#include <hip/hip_runtime.h>

#define D 64
#define WQ_BITS 15
#define WQ_MAX 32767.0f
#define NSHARDS 8
#define SCB 4096        // scatter role blocks (8 shards x 512 slices; r1-verified)
#define CAP32 32        // bucket capacity (deg~Poisson(16); P(>32)~1e-4)

typedef int    int4v    __attribute__((ext_vector_type(4)));
typedef float  float4v  __attribute__((ext_vector_type(4)));

__device__ __forceinline__ ushort f2bf(float x) {
    unsigned u = __float_as_uint(x);
    unsigned r = (u + 0x7fff + ((u >> 16) & 1)) >> 16;  // round-to-nearest-even
    return (ushort)r;
}
__device__ __forceinline__ float bf2f(ushort u) {
    return __uint_as_float(((unsigned)u) << 16);
}

// ---------------------------------------------------------------------------
// Round-16 combined kernel: role-split single dispatch.
//   blocks [0, gemmB)      : fused GEMM  out = b + h@W1^T (fp32), g = h@W2^T (bf16)
//   blocks [gemmB, +SCB)   : r1-verified shard scatter (78us standalone)
// Rationale: scatter is atomic-throughput-bound (1.6M returning atomicAdds /
// 8 XCDs ~ 83us floor) with idle VALU (6%); gemm is 30us of pure VALU. No
// data dependency -> overlap inside ONE dispatch (events/streams banned).
// Coherence ledger unchanged: node-sharded scatter keeps each pairs row
// single-XCD-dirty (r2: cross-XCD plain stores corrupt; r3: agent-scope
// stores write-through 64B/store; r4: XCD-partition L2-churn).
__global__ __launch_bounds__(256) void combined_kernel(
    const int* __restrict__ src, const int* __restrict__ dst,
    const float* __restrict__ w, int* __restrict__ cursor,
    unsigned* __restrict__ ovBits, unsigned* __restrict__ pairs,
    const float* __restrict__ h, const float* __restrict__ W,
    const float* __restrict__ b, float* __restrict__ out,
    ushort* __restrict__ g, int E, int N, int gemmB)
{
    __shared__ float Wt[128 * 64];  // gemm role only (48KB total w/ Xt)
    __shared__ float Xt[64 * 64];

    if ((int)blockIdx.x < gemmB) {
        // ---------------- GEMM role (r0-r5 known-good body) ----------------
        int tid = threadIdx.x;
        for (int idx = tid; idx < 128 * 64; idx += 256) {
            int j = idx & 63;
            int k = idx >> 6;
            Wt[k * 64 + j] = W[j * 128 + k];
        }
        int n0blk = blockIdx.x * 64;
        {
            int n = tid & 63;
            int krow = tid >> 6;
            int nn = min(n0blk + n, N - 1);
            #pragma unroll
            for (int c = 0; c < 4; ++c) {
                int k0 = (krow + c * 4) * 4;
                float4 v = *(const float4*)&h[(size_t)nn * D + k0];
                Xt[(k0 + 0) * 64 + n] = v.x;
                Xt[(k0 + 1) * 64 + n] = v.y;
                Xt[(k0 + 2) * 64 + n] = v.z;
                Xt[(k0 + 3) * 64 + n] = v.w;
            }
        }
        __syncthreads();

        int j0 = (tid & 15) * 4;
        int nb = (tid >> 4) * 4;

        float4 bv = *(const float4*)&b[j0];
        float accS[4][4], accG[4][4];
        #pragma unroll
        for (int i = 0; i < 4; ++i) {
            accS[i][0] = bv.x; accS[i][1] = bv.y;
            accS[i][2] = bv.z; accS[i][3] = bv.w;
            accG[i][0] = 0.f;  accG[i][1] = 0.f;
            accG[i][2] = 0.f;  accG[i][3] = 0.f;
        }

        #pragma unroll 4
        for (int k = 0; k < 64; ++k) {
            float4 xv = *(const float4*)&Xt[k * 64 + nb];
            float4 w1 = *(const float4*)&Wt[k * 64 + j0];
            float4 w2 = *(const float4*)&Wt[(k + 64) * 64 + j0];
            #pragma unroll
            for (int i = 0; i < 4; ++i) {
                float x = (&xv.x)[i];
                accS[i][0] += x * w1.x; accS[i][1] += x * w1.y;
                accS[i][2] += x * w1.z; accS[i][3] += x * w1.w;
                accG[i][0] += x * w2.x; accG[i][1] += x * w2.y;
                accG[i][2] += x * w2.z; accG[i][3] += x * w2.w;
            }
        }

        #pragma unroll
        for (int i = 0; i < 4; ++i) {
            int n = n0blk + nb + i;
            if (n < N) {
                *(float4*)&out[(size_t)n * D + j0] =
                    make_float4(accS[i][0], accS[i][1], accS[i][2], accS[i][3]);
                ushort4 gv;
                gv.x = f2bf(accG[i][0]); gv.y = f2bf(accG[i][1]);
                gv.z = f2bf(accG[i][2]); gv.w = f2bf(accG[i][3]);
                *(ushort4*)&g[(size_t)n * D + j0] = gv;
            }
        }
    } else {
        // ---------------- scatter role (r1-verified body) ----------------
        int bid     = blockIdx.x - gemmB;
        int shard   = bid & (NSHARDS - 1);
        int slice   = bid >> 3;
        int nSlices = SCB >> 3;
        int n8 = (N + NSHARDS - 1) / NSHARDS;
        int lo = shard * n8;
        int hi = min(N, lo + n8);

        int e4 = E >> 2;
        for (int gi = slice * 256 + threadIdx.x; gi < e4; gi += nSlices * 256) {
            int e0 = gi * 4;
            int4v   d4 = __builtin_nontemporal_load((const int4v*)&dst[e0]);
            int4v   s4 = __builtin_nontemporal_load((const int4v*)&src[e0]);
            float4v w4 = __builtin_nontemporal_load((const float4v*)&w[e0]);
            #pragma unroll
            for (int i = 0; i < 4; ++i) {
                int d = d4[i];
                if (d >= lo && d < hi) {
                    int e = e0 + i;
                    int pos = atomicAdd(&cursor[d], 1);
                    if (pos < CAP32) {
                        float wv = fminf(fmaxf(w4[i], 0.f), 1.f);
                        unsigned wq = (unsigned)(wv * WQ_MAX + 0.5f);
                        pairs[(size_t)d * CAP32 + pos] =
                            ((unsigned)s4[i] << WQ_BITS) | wq;
                    } else {
                        atomicOr(&ovBits[e >> 5], 1u << (e & 31));
                    }
                }
            }
        }
        for (int e = e4 * 4 + slice * 256 + threadIdx.x; e < E;
             e += nSlices * 256) {
            int d = dst[e];
            if (d >= lo && d < hi) {
                int pos = atomicAdd(&cursor[d], 1);
                if (pos < CAP32) {
                    float wv = fminf(fmaxf(w[e], 0.f), 1.f);
                    unsigned wq = (unsigned)(wv * WQ_MAX + 0.5f);
                    pairs[(size_t)d * CAP32 + pos] =
                        ((unsigned)src[e] << WQ_BITS) | wq;
                } else {
                    atomicOr(&ovBits[e >> 5], 1u << (e & 31));
                }
            }
        }
    }
}

// ---------------------------------------------------------------------------
// Final: out[n] += sum over bucket(n) of w_e * g_bf16[src_e]. One wave/node,
// MLP-16 batched gathers (r1/r3 verified, ~115-135us: L2-line-request-bound).
__global__ __launch_bounds__(256) void final_agg_kernel(
    const ushort* __restrict__ g, const unsigned* __restrict__ pairs,
    const int* __restrict__ cursor, float* __restrict__ out, int N)
{
    int wave = threadIdx.x >> 6;
    int lane = threadIdx.x & 63;
    int n = blockIdx.x * 4 + wave;
    if (n >= N) return;
    int cnt = min(cursor[n], CAP32);
    unsigned mycode = (lane < CAP32) ? pairs[(size_t)n * CAP32 + lane] : 0u;
    float acc = out[(size_t)n * D + lane];

    const float wscale = 1.0f / WQ_MAX;
    int j = 0;
    for (; j + 16 <= cnt; j += 16) {
        unsigned c[16];
        float v[16];
        #pragma unroll
        for (int u = 0; u < 16; ++u) c[u] = __shfl(mycode, j + u);
        #pragma unroll
        for (int u = 0; u < 16; ++u)
            v[u] = bf2f(g[(size_t)(c[u] >> WQ_BITS) * D + lane]);
        #pragma unroll
        for (int u = 0; u < 16; ++u)
            acc += (float)(c[u] & 0x7fffu) * wscale * v[u];
    }
    for (; j + 4 <= cnt; j += 4) {
        unsigned c[4];
        float v[4];
        #pragma unroll
        for (int u = 0; u < 4; ++u) c[u] = __shfl(mycode, j + u);
        #pragma unroll
        for (int u = 0; u < 4; ++u)
            v[u] = bf2f(g[(size_t)(c[u] >> WQ_BITS) * D + lane]);
        #pragma unroll
        for (int u = 0; u < 4; ++u)
            acc += (float)(c[u] & 0x7fffu) * wscale * v[u];
    }
    for (; j < cnt; ++j) {
        unsigned c = __shfl(mycode, j);
        acc += (float)(c & 0x7fffu) * wscale *
               bf2f(g[(size_t)(c >> WQ_BITS) * D + lane]);
    }
    out[(size_t)n * D + lane] = acc;
}

// ---------------------------------------------------------------------------
// Overflow cleanup — r0-r3 per-THREAD word scan (~3 dependent loads/thread,
// ~3us). Round-6 post-mortem: the r5 per-WAVE scan (195 serial loads/wave)
// cost ~125us — the hidden regression of rounds 5-6.
__global__ __launch_bounds__(256) void overflow_kernel(
    const unsigned* __restrict__ ovBits, const int* __restrict__ src,
    const int* __restrict__ dst, const float* __restrict__ w,
    const ushort* __restrict__ g, float* __restrict__ out, int numWords)
{
    int idx = blockIdx.x * 256 + threadIdx.x;
    for (int wi = idx; wi < numWords; wi += gridDim.x * 256) {
        unsigned bits = ovBits[wi];
        while (bits) {
            int bit = __ffs(bits) - 1;
            bits &= bits - 1;
            int e = wi * 32 + bit;
            int s = src[e], d = dst[e];
            float wv = w[e];
            for (int f = 0; f < D; ++f)
                atomicAdd(&out[(size_t)d * D + f], wv * bf2f(g[(size_t)s * D + f]));
        }
    }
}

// ---------------------------------------------------------------------------
// Fallback path (small ws / big N): round-1 kernels, known-good.
__global__ __launch_bounds__(256) void edge_scatter_kernel(
    const float* __restrict__ h, const float* __restrict__ w,
    const int* __restrict__ src, const int* __restrict__ dst,
    float* __restrict__ agg, int E)
{
    int e = blockIdx.x * 4 + (threadIdx.x >> 6);
    int lane = threadIdx.x & 63;
    if (e >= E) return;
    float val = w[e] * h[(size_t)src[e] * D + lane];
    atomicAdd(&agg[(size_t)dst[e] * D + lane], val);
}

__global__ __launch_bounds__(256) void out_linear_kernel(
    const float* __restrict__ h, const float* __restrict__ agg,
    const float* __restrict__ W, const float* __restrict__ b,
    float* __restrict__ out, int N)
{
    __shared__ float Wt[128 * 64];
    int lane = threadIdx.x & 63;
    int waveInBlock = threadIdx.x >> 6;
    int wavesPerBlock = blockDim.x >> 6;
    for (int idx = threadIdx.x; idx < 128 * 64; idx += blockDim.x) {
        int j = idx & 63;
        int k = idx >> 6;
        Wt[k * 64 + j] = W[j * 128 + k];
    }
    __syncthreads();
    float bj = b[lane];
    int wavesPerGrid = gridDim.x * wavesPerBlock;
    for (int n = blockIdx.x * wavesPerBlock + waveInBlock; n < N; n += wavesPerGrid) {
        float hreg = h[(size_t)n * D + lane];
        float areg = agg[(size_t)n * D + lane];
        float acc = bj;
        #pragma unroll
        for (int k = 0; k < 64; ++k) {
            float hk = __shfl(hreg, k, 64);
            float ak = __shfl(areg, k, 64);
            acc += hk * Wt[k * 64 + lane];
            acc += ak * Wt[(k + 64) * 64 + lane];
        }
        out[(size_t)n * D + lane] = acc;
    }
}

// ---------------------------------------------------------------------------
extern "C" void kernel_launch(void* const* d_in, const int* in_sizes, int n_in,
                              void* d_out, int out_size, void* d_ws, size_t ws_size,
                              hipStream_t stream) {
    const float* h   = (const float*)d_in[0];
    const float* w   = (const float*)d_in[1];
    const int*   src = (const int*)d_in[2];
    const int*   dst = (const int*)d_in[3];
    const float* W   = (const float*)d_in[4];
    const float* b   = (const float*)d_in[5];
    float* out = (float*)d_out;

    int N = in_sizes[0] / D;
    int E = in_sizes[1];
    int numWords = (E + 31) / 32;

    auto align256 = [](size_t x) { return (x + 255) & ~(size_t)255; };
    size_t cursorB = align256((size_t)N * 4);
    size_t ovB     = align256((size_t)numWords * 4);
    size_t pairsB  = align256((size_t)N * CAP32 * 4);
    size_t gB      = align256((size_t)N * D * 2);
    size_t need = cursorB + ovB + pairsB + gB;

    if (ws_size >= need && N <= (1 << 17)) {
        char* p = (char*)d_ws;
        int*      cursor = (int*)p;       p += cursorB;
        unsigned* ovBits = (unsigned*)p;  p += ovB;
        unsigned* pairs  = (unsigned*)p;  p += pairsB;
        ushort*   g      = (ushort*)p;

        hipMemsetAsync(cursor, 0, cursorB + ovB, stream);

        int gemmB = (N + 63) / 64;
        combined_kernel<<<gemmB + SCB, 256, 0, stream>>>(
            src, dst, w, cursor, ovBits, pairs, h, W, b, out, g, E, N, gemmB);
        final_agg_kernel<<<(N + 3) / 4, 256, 0, stream>>>(g, pairs, cursor,
                                                          out, N);
        overflow_kernel<<<64, 256, 0, stream>>>(ovBits, src, dst, w, g, out,
                                                numWords);
    } else {
        float* agg = out;
        hipMemsetAsync(agg, 0, (size_t)N * D * 4, stream);
        edge_scatter_kernel<<<(E + 3) / 4, 256, 0, stream>>>(h, w, src, dst, agg, E);
        out_linear_kernel<<<2048, 256, 0, stream>>>(h, agg, W, b, out, N);
    }
}